// Round 16
// baseline (454.145 us; speedup 1.0000x reference)
//
#include <hip/hip_runtime.h>

#define N_NODES 50000
#define N_EDGES 800000
#define IN_DIM  1200
#define KP      1216               // Wb padded K
#define OUT_DIM 300
#define BNP     320                // Wb padded rows
#define XBS     304                // xb row stride (bf16)
#define BM      48
#define NKT     38                 // K-steps of 32
#define GRID_M  ((N_NODES + BM - 1) / BM)   // 1042 -> 4.07 blocks/CU

typedef __attribute__((ext_vector_type(8))) short short8;
typedef __attribute__((ext_vector_type(4))) short short4v;
typedef __attribute__((ext_vector_type(4))) float f32x4;

__device__ __forceinline__ short f2bf(float f) {
  unsigned u = __builtin_bit_cast(unsigned, f);
  u += 0x7fffu + ((u >> 16) & 1u);            // RNE
  return (short)(u >> 16);
}
__device__ __forceinline__ float bf2f(unsigned short h) {
  return __builtin_bit_cast(float, (unsigned)h << 16);
}
__device__ __forceinline__ float lrelu(float v) { return v > 0.f ? v : 0.2f * v; }

__device__ __forceinline__ float wredMaxF(float v) {
  #pragma unroll
  for (int o = 32; o > 0; o >>= 1) v = fmaxf(v, __shfl_xor(v, o));
  return v;
}
__device__ __forceinline__ float wredSumF(float v) {
  #pragma unroll
  for (int o = 32; o > 0; o >>= 1) v += __shfl_xor(v, o);
  return v;
}

// ---------------- W -> bf16, padded [320][1216]
__global__ __launch_bounds__(256) void wconv(const float* __restrict__ W,
                                             unsigned short* __restrict__ Wb) {
  int f = blockIdx.x * 256 + threadIdx.x;
  if (f >= BNP * KP / 8) return;
  int n = (f * 8) / KP, c = (f * 8) % KP;
  short8 v = {0,0,0,0,0,0,0,0};
  if (n < OUT_DIM && c < IN_DIM) {
    const float4* p = reinterpret_cast<const float4*>(W + (size_t)n * IN_DIM + c);
    float4 f0 = p[0], f1 = p[1];
    v[0]=f2bf(f0.x); v[1]=f2bf(f0.y); v[2]=f2bf(f0.z); v[3]=f2bf(f0.w);
    v[4]=f2bf(f1.x); v[5]=f2bf(f1.y); v[6]=f2bf(f1.z); v[7]=f2bf(f1.w);
  }
  *reinterpret_cast<short8*>(&Wb[(size_t)n * KP + c]) = v;
}

// ---------------- GEMM: xb = z @ W^T. BM=48, BN=320, BK=32, 4 waves N-split.
// Theory under test: z-delivery BW scales with resident blocks (R11: 2.5 TB/s
// at 4-5 blk/CU vs 1.6 at 2-3). Grid 1042 = 4.07 blocks/CU; LDS only 6 KB
// (A dbuf); B per-wave from L2-hot Wb; no launch_bounds register strangling.
__global__ __launch_bounds__(256) void gemm_x(const float* __restrict__ z,
                                              const unsigned short* __restrict__ Wb,
                                              const float* __restrict__ att_s,
                                              const float* __restrict__ att_d,
                                              unsigned short* __restrict__ xb,
                                              float* __restrict__ a_s,
                                              float* __restrict__ a_d) {
  __shared__ __align__(16) unsigned short As[2][BM * 32];   // 2 x 3 KB

  const int tid  = threadIdx.x;
  const int lane = tid & 63;
  const int wid  = tid >> 6;           // 0..3, owns cols 80*wid..
  const int lr   = lane & 15;
  const int lg   = lane >> 4;
  const int lrs  = (lr >> 1) & 3;      // read-side swizzle term
  const int m0   = blockIdx.x * BM;

  f32x4 zero4 = {0.f, 0.f, 0.f, 0.f};
  const float4 fz4 = make_float4(0.f, 0.f, 0.f, 0.f);
  f32x4 acc[3][5];
  #pragma unroll
  for (int mf = 0; mf < 3; ++mf)
    #pragma unroll
    for (int nj = 0; nj < 5; ++nj) acc[mf][nj] = zero4;

  // A staging: 384 float4 slots; slot s: row = s>>3 (0..47), f4c = s&7.
  // thread t handles slot t, and slot t+256 if t<128.
  const int r0_ = tid >> 3,         f0_ = tid & 7;
  const int r1_ = (tid + 256) >> 3, f1_ = (tid + 256) & 7;
  const bool has2 = tid < 128;
  float4 ga0, ga1;

  // B lane pointer: row = 80*wid + 16*nj + lr, k = kt*32 + lg*8
  const unsigned short* bp = Wb + (size_t)(80 * wid + lr) * KP + lg * 8;

  #define LOADA(KT)                                                           \
    {                                                                         \
      int k0 = (KT) * 32 + f0_ * 4;                                           \
      int m  = m0 + r0_;                                                      \
      ga0 = (m < N_NODES && k0 + 4 <= IN_DIM)                                 \
        ? *reinterpret_cast<const float4*>(z + (size_t)m * IN_DIM + k0) : fz4;\
      if (has2) {                                                             \
        int k1 = (KT) * 32 + f1_ * 4;                                         \
        int m1 = m0 + r1_;                                                    \
        ga1 = (m1 < N_NODES && k1 + 4 <= IN_DIM)                              \
          ? *reinterpret_cast<const float4*>(z + (size_t)m1 * IN_DIM + k1) : fz4; \
      }                                                                       \
    }

  #define WRITEA(BUF)                                                         \
    {                                                                         \
      short4v v;                                                              \
      v[0]=f2bf(ga0.x); v[1]=f2bf(ga0.y); v[2]=f2bf(ga0.z); v[3]=f2bf(ga0.w); \
      int c2 = (f0_ >> 1) ^ ((r0_ >> 1) & 3);                                 \
      *reinterpret_cast<short4v*>(&As[BUF][r0_ * 32 + c2 * 8 + (f0_ & 1) * 4]) = v; \
      if (has2) {                                                             \
        short4v w2;                                                           \
        w2[0]=f2bf(ga1.x); w2[1]=f2bf(ga1.y); w2[2]=f2bf(ga1.z); w2[3]=f2bf(ga1.w); \
        int c3 = (f1_ >> 1) ^ ((r1_ >> 1) & 3);                               \
        *reinterpret_cast<short4v*>(&As[BUF][r1_ * 32 + c3 * 8 + (f1_ & 1) * 4]) = w2; \
      }                                                                       \
    }

  LOADA(0);
  WRITEA(0);
  __syncthreads();

  #pragma unroll 1
  for (int kt = 0; kt < NKT; ++kt) {
    const int cur = kt & 1;
    if (kt < NKT - 1) { LOADA(kt + 1); }   // z loads in flight across compute

    // B frags straight from L2 (Wb is L2-hot: 0.78 MB, replicated per XCD)
    const unsigned short* bk = bp + kt * 32;
    short8 b0 = *reinterpret_cast<const short8*>(bk);
    short8 b1 = *reinterpret_cast<const short8*>(bk + (size_t)16 * KP);
    short8 b2 = *reinterpret_cast<const short8*>(bk + (size_t)32 * KP);
    short8 b3 = *reinterpret_cast<const short8*>(bk + (size_t)48 * KP);
    short8 b4 = *reinterpret_cast<const short8*>(bk + (size_t)64 * KP);

    // A frags: row = mf*16 + lr; phys chunk = lg ^ lrs (verified conflict-free)
    short8 a0 = *reinterpret_cast<const short8*>(&As[cur][(lr) * 32 + (lg ^ lrs) * 8]);
    short8 a1 = *reinterpret_cast<const short8*>(&As[cur][(16 + lr) * 32 + (lg ^ lrs) * 8]);
    short8 a2 = *reinterpret_cast<const short8*>(&As[cur][(32 + lr) * 32 + (lg ^ lrs) * 8]);

    acc[0][0] = __builtin_amdgcn_mfma_f32_16x16x32_bf16(a0, b0, acc[0][0], 0, 0, 0);
    acc[1][0] = __builtin_amdgcn_mfma_f32_16x16x32_bf16(a1, b0, acc[1][0], 0, 0, 0);
    acc[2][0] = __builtin_amdgcn_mfma_f32_16x16x32_bf16(a2, b0, acc[2][0], 0, 0, 0);
    acc[0][1] = __builtin_amdgcn_mfma_f32_16x16x32_bf16(a0, b1, acc[0][1], 0, 0, 0);
    acc[1][1] = __builtin_amdgcn_mfma_f32_16x16x32_bf16(a1, b1, acc[1][1], 0, 0, 0);
    acc[2][1] = __builtin_amdgcn_mfma_f32_16x16x32_bf16(a2, b1, acc[2][1], 0, 0, 0);
    acc[0][2] = __builtin_amdgcn_mfma_f32_16x16x32_bf16(a0, b2, acc[0][2], 0, 0, 0);
    acc[1][2] = __builtin_amdgcn_mfma_f32_16x16x32_bf16(a1, b2, acc[1][2], 0, 0, 0);
    acc[2][2] = __builtin_amdgcn_mfma_f32_16x16x32_bf16(a2, b2, acc[2][2], 0, 0, 0);
    acc[0][3] = __builtin_amdgcn_mfma_f32_16x16x32_bf16(a0, b3, acc[0][3], 0, 0, 0);
    acc[1][3] = __builtin_amdgcn_mfma_f32_16x16x32_bf16(a1, b3, acc[1][3], 0, 0, 0);
    acc[2][3] = __builtin_amdgcn_mfma_f32_16x16x32_bf16(a2, b3, acc[2][3], 0, 0, 0);
    acc[0][4] = __builtin_amdgcn_mfma_f32_16x16x32_bf16(a0, b4, acc[0][4], 0, 0, 0);
    acc[1][4] = __builtin_amdgcn_mfma_f32_16x16x32_bf16(a1, b4, acc[1][4], 0, 0, 0);
    acc[2][4] = __builtin_amdgcn_mfma_f32_16x16x32_bf16(a2, b4, acc[2][4], 0, 0, 0);

    if (kt < NKT - 1) {
      WRITEA(cur ^ 1);
      __syncthreads();
    }
  }
  #undef LOADA
  #undef WRITEA

  // ---- epilogue: bf16 x store + fused logits, cross-wave (4 col-waves) reduce
  __syncthreads();
  float* red = reinterpret_cast<float*>(&As[0][0]);  // [2 sd][4 wid][48 rows] = 1.5 KB

  float ps[3][4], pd[3][4];
  #pragma unroll
  for (int mf = 0; mf < 3; ++mf)
    #pragma unroll
    for (int jj = 0; jj < 4; ++jj) { ps[mf][jj] = 0.f; pd[mf][jj] = 0.f; }

  #pragma unroll
  for (int nj = 0; nj < 5; ++nj) {
    int c = wid * 80 + nj * 16 + lr;
    bool cv = c < OUT_DIM;
    float vs = cv ? att_s[c] : 0.f;
    float vd = cv ? att_d[c] : 0.f;
    #pragma unroll
    for (int mf = 0; mf < 3; ++mf) {
      #pragma unroll
      for (int jj = 0; jj < 4; ++jj) {
        float val = acc[mf][nj][jj];
        int r = m0 + mf * 16 + 4 * lg + jj;
        if (cv && r < N_NODES) xb[(size_t)r * XBS + c] = (unsigned short)f2bf(val);
        ps[mf][jj] += val * vs;
        pd[mf][jj] += val * vd;
      }
    }
  }
  #pragma unroll
  for (int mf = 0; mf < 3; ++mf)
    #pragma unroll
    for (int jj = 0; jj < 4; ++jj) {
      #pragma unroll
      for (int o = 8; o > 0; o >>= 1) {
        ps[mf][jj] += __shfl_xor(ps[mf][jj], o);
        pd[mf][jj] += __shfl_xor(pd[mf][jj], o);
      }
      if (lr == 0) {
        int rr = mf * 16 + 4 * lg + jj;   // 0..47
        red[wid * 48 + rr]       = ps[mf][jj];
        red[192 + wid * 48 + rr] = pd[mf][jj];
      }
    }
  __syncthreads();
  if (tid < 48) {
    int r = m0 + tid;
    if (r < N_NODES)
      a_s[r] = red[tid] + red[48 + tid] + red[96 + tid] + red[144 + tid];
  } else if (tid < 96) {
    int t = tid - 48, r = m0 + t;
    if (r < N_NODES)
      a_d[r] = red[192 + t] + red[192 + 48 + t] + red[192 + 96 + t] + red[192 + 144 + t];
  }
}

// ---------------- CSR build (edges only; self-loops handled analytically)
__global__ void hist(const int* __restrict__ ei, int* __restrict__ deg) {
  int e = blockIdx.x * blockDim.x + threadIdx.x;
  if (e < N_EDGES) {
    unsigned dst = (unsigned)ei[N_EDGES + e];
    if (dst < N_NODES) atomicAdd(&deg[dst], 1);
  }
}

#define SCAN_B 1024
#define NBLK   49

__global__ __launch_bounds__(SCAN_B) void scan1(const int* __restrict__ deg,
                                                int* __restrict__ bsum) {
  int i = blockIdx.x * SCAN_B + threadIdx.x;
  int v = (i < N_NODES) ? deg[i] : 0;
  #pragma unroll
  for (int o = 32; o > 0; o >>= 1) v += __shfl_xor(v, o);
  __shared__ int wt[16];
  if ((threadIdx.x & 63) == 0) wt[threadIdx.x >> 6] = v;
  __syncthreads();
  if (threadIdx.x == 0) {
    int t = 0;
    #pragma unroll
    for (int w = 0; w < 16; ++w) t += wt[w];
    bsum[blockIdx.x] = t;
  }
}

__global__ void scan2(const int* __restrict__ bsum, int* __restrict__ bex,
                      int* __restrict__ offs) {
  int l = threadIdx.x;
  int v = (l < NBLK) ? bsum[l] : 0;
  int incl = v;
  #pragma unroll
  for (int off = 1; off < 64; off <<= 1) {
    int u = __shfl_up(incl, off);
    if (l >= off) incl += u;
  }
  if (l < NBLK) bex[l] = incl - v;
  if (l == NBLK - 1) offs[N_NODES] = incl;
}

__global__ __launch_bounds__(SCAN_B) void scan3(const int* __restrict__ deg,
                                                const int* __restrict__ bex,
                                                int* __restrict__ offs,
                                                int* __restrict__ cursor) {
  int tid = threadIdx.x;
  int i = blockIdx.x * SCAN_B + tid;
  int lane = tid & 63, wid = tid >> 6;
  int v = (i < N_NODES) ? deg[i] : 0;
  int incl = v;
  #pragma unroll
  for (int off = 1; off < 64; off <<= 1) {
    int u = __shfl_up(incl, off);
    if (lane >= off) incl += u;
  }
  __shared__ int wt[16];
  if (lane == 63) wt[wid] = incl;
  __syncthreads();
  if (tid < 16) {
    int t = wt[tid];
    int sc = t;
    #pragma unroll
    for (int off = 1; off < 16; off <<= 1) {
      int u = __shfl_up(sc, off);
      if (tid >= off) sc += u;
    }
    wt[tid] = sc - t;
  }
  __syncthreads();
  int excl = incl - v + wt[wid] + bex[blockIdx.x];
  if (i < N_NODES) { offs[i] = excl; cursor[i] = excl; }
}

__global__ void fill(const int* __restrict__ ei, int* __restrict__ cursor,
                     int* __restrict__ srcs) {
  int e = blockIdx.x * blockDim.x + threadIdx.x;
  if (e < N_EDGES) {
    unsigned dst = (unsigned)ei[N_EDGES + e];
    unsigned src = (unsigned)ei[e];
    if (dst < N_NODES && src < N_NODES) {
      int pos = atomicAdd(&cursor[dst], 1);
      srcs[pos] = (int)src;
    }
  }
}

// ---------------- per-node softmax stats (m, 1/s) — wave per node
__global__ __launch_bounds__(256) void minv_k(const float* __restrict__ a_s,
                                              const float* __restrict__ a_d,
                                              const int* __restrict__ offs,
                                              const int* __restrict__ srcs,
                                              float2* __restrict__ minv) {
  int node = blockIdx.x * 4 + (threadIdx.x >> 6);
  if (node >= N_NODES) return;
  int lane = threadIdx.x & 63;
  int beg = offs[node], end = offs[node + 1];
  float adi = a_d[node];
  float eself = lrelu(a_s[node] + adi);

  float m = eself;
  for (int k = beg + lane; k < end; k += 64)
    m = fmaxf(m, lrelu(a_s[srcs[k]] + adi));
  m = wredMaxF(m);

  float s = 0.f;
  for (int k = beg + lane; k < end; k += 64)
    s += expf(lrelu(a_s[srcs[k]] + adi) - m);
  s = wredSumF(s) + expf(eself - m);
  if (lane == 0) minv[node] = make_float2(m, 1.0f / s);
}

// ---------------- streaming weighted gather: thread = (node, 20-col chunk)
#define CCH 15
__global__ __launch_bounds__(256) void aggregate(const unsigned short* __restrict__ xb,
                                                 const float* __restrict__ a_s,
                                                 const float* __restrict__ a_d,
                                                 const float2* __restrict__ minv,
                                                 const int* __restrict__ offs,
                                                 const int* __restrict__ srcs,
                                                 const float* __restrict__ bias,
                                                 float* __restrict__ out) {
  unsigned wi = blockIdx.x * 256u + threadIdx.x;
  if (wi >= (unsigned)N_NODES * CCH) return;
  unsigned node = wi / CCH;
  unsigned cc = wi - node * CCH;           // cols 20cc..20cc+19

  int beg = offs[node], end = offs[node + 1];
  float2 mi = minv[node];
  const float m = mi.x, inv = mi.y;
  const float adi = a_d[node];
  const float wself = expf(lrelu(a_s[node] + adi) - m) * inv;

  const unsigned short* xcol = xb + 20u * cc;

  float acc[20];
  {
    const unsigned short* xr = xcol + (size_t)node * XBS;
    #pragma unroll
    for (int q = 0; q < 5; ++q) {
      ushort4 xv = *reinterpret_cast<const ushort4*>(xr + 4 * q);
      acc[4*q+0] = wself * bf2f(xv.x);
      acc[4*q+1] = wself * bf2f(xv.y);
      acc[4*q+2] = wself * bf2f(xv.z);
      acc[4*q+3] = wself * bf2f(xv.w);
    }
  }

  for (int k = beg; k < end; ++k) {
    int sj = srcs[k];
    float w = expf(lrelu(a_s[sj] + adi) - m) * inv;
    const unsigned short* xr = xcol + (size_t)sj * XBS;
    #pragma unroll
    for (int q = 0; q < 5; ++q) {
      ushort4 xv = *reinterpret_cast<const ushort4*>(xr + 4 * q);
      acc[4*q+0] += w * bf2f(xv.x);
      acc[4*q+1] += w * bf2f(xv.y);
      acc[4*q+2] += w * bf2f(xv.z);
      acc[4*q+3] += w * bf2f(xv.w);
    }
  }
  float* op = out + (size_t)node * OUT_DIM + 20u * cc;
  const float* bp = bias + 20u * cc;
  #pragma unroll
  for (int q = 0; q < 5; ++q) {
    float4 b = *reinterpret_cast<const float4*>(bp + 4 * q);
    float4 o = {acc[4*q] + b.x, acc[4*q+1] + b.y, acc[4*q+2] + b.z, acc[4*q+3] + b.w};
    *reinterpret_cast<float4*>(op + 4 * q) = o;
  }
}

extern "C" void kernel_launch(void* const* d_in, const int* in_sizes, int n_in,
                              void* d_out, int out_size, void* d_ws, size_t ws_size,
                              hipStream_t stream) {
  const float* z     = (const float*)d_in[0];
  const int*   ei    = (const int*)d_in[1];     // int64 in ref -> int32 on the wire
  const float* W     = (const float*)d_in[2];
  const float* att_s = (const float*)d_in[3];
  const float* att_d = (const float*)d_in[4];
  const float* bias  = (const float*)d_in[5];
  float* out = (float*)d_out;

  char* ws = (char*)d_ws;
  size_t off = 0;
  unsigned short* xb = (unsigned short*)(ws + off); off += (size_t)N_NODES * XBS * 2;  // 30.4 MB
  unsigned short* Wb = (unsigned short*)(ws + off); off += (size_t)BNP * KP * 2;
  float*  a_s  = (float*)(ws + off);  off += 50048 * 4;
  float*  a_d  = (float*)(ws + off);  off += 50048 * 4;
  int*    deg  = (int*)(ws + off);    off += 50048 * 4;
  int*    offs = (int*)(ws + off);    off += 50056 * 4;
  int*    cur  = (int*)(ws + off);    off += 50048 * 4;
  int*    bsum = (int*)(ws + off);    off += 64 * 4;
  int*    bex  = (int*)(ws + off);    off += 64 * 4;
  int*    srcs = (int*)(ws + off);    off += (size_t)N_EDGES * 4;
  float2* minv = (float2*)(ws + off); off += (size_t)50048 * 8;

  (void)hipMemsetAsync(deg, 0, N_NODES * 4, stream);

  wconv<<<(BNP * KP / 8 + 255) / 256, 256, 0, stream>>>(W, Wb);
  gemm_x<<<GRID_M, 256, 0, stream>>>(z, Wb, att_s, att_d, xb, a_s, a_d);
  hist<<<(N_EDGES + 255) / 256, 256, 0, stream>>>(ei, deg);
  scan1<<<NBLK, SCAN_B, 0, stream>>>(deg, bsum);
  scan2<<<1, 64, 0, stream>>>(bsum, bex, offs);
  scan3<<<NBLK, SCAN_B, 0, stream>>>(deg, bex, offs, cur);
  fill<<<(N_EDGES + 255) / 256, 256, 0, stream>>>(ei, cur, srcs);
  minv_k<<<(N_NODES + 3) / 4, 256, 0, stream>>>(a_s, a_d, offs, srcs, minv);
  aggregate<<<((unsigned)N_NODES * CCH + 255) / 256, 256, 0, stream>>>(
      xb, a_s, a_d, minv, offs, srcs, bias, out);
}

// Round 17
// 442.499 us; speedup vs baseline: 1.0263x; 1.0263x over previous
//
#include <hip/hip_runtime.h>

#define N_NODES 50000
#define N_EDGES 800000
#define IN_DIM  1200
#define KP      1216               // Wb padded K
#define OUT_DIM 300
#define BNP     320                // Wb padded rows
#define XBS     304                // xb row stride (bf16)
#define BM      128
#define NKT     38                 // K-steps of 32
#define GRID_M  ((N_NODES + BM - 1) / BM)   // 391

typedef __attribute__((ext_vector_type(8))) short short8;
typedef __attribute__((ext_vector_type(4))) float f32x4;

__device__ __forceinline__ short f2bf(float f) {
  unsigned u = __builtin_bit_cast(unsigned, f);
  u += 0x7fffu + ((u >> 16) & 1u);            // RNE
  return (short)(u >> 16);
}
__device__ __forceinline__ float bf2f(unsigned short h) {
  return __builtin_bit_cast(float, (unsigned)h << 16);
}
__device__ __forceinline__ float lrelu(float v) { return v > 0.f ? v : 0.2f * v; }

__device__ __forceinline__ float wredMaxF(float v) {
  #pragma unroll
  for (int o = 32; o > 0; o >>= 1) v = fmaxf(v, __shfl_xor(v, o));
  return v;
}
__device__ __forceinline__ float wredSumF(float v) {
  #pragma unroll
  for (int o = 32; o > 0; o >>= 1) v += __shfl_xor(v, o);
  return v;
}

// async 16B/lane global->LDS DMA; lds dest wave-uniform (HW adds lane*16)
__device__ __forceinline__ void gl_lds16(const unsigned short* g, unsigned short* l) {
  __builtin_amdgcn_global_load_lds(
      (const __attribute__((address_space(1))) unsigned int*)g,
      (__attribute__((address_space(3))) unsigned int*)l, 16, 0, 0);
}

// ---------------- W -> bf16, padded [320][1216]
__global__ __launch_bounds__(256) void wconv(const float* __restrict__ W,
                                             unsigned short* __restrict__ Wb) {
  int f = blockIdx.x * 256 + threadIdx.x;
  if (f >= BNP * KP / 8) return;
  int n = (f * 8) / KP, c = (f * 8) % KP;
  short8 v = {0,0,0,0,0,0,0,0};
  if (n < OUT_DIM && c < IN_DIM) {
    const float4* p = reinterpret_cast<const float4*>(W + (size_t)n * IN_DIM + c);
    float4 f0 = p[0], f1 = p[1];
    v[0]=f2bf(f0.x); v[1]=f2bf(f0.y); v[2]=f2bf(f0.z); v[3]=f2bf(f0.w);
    v[4]=f2bf(f1.x); v[5]=f2bf(f1.y); v[6]=f2bf(f1.z); v[7]=f2bf(f1.w);
  }
  *reinterpret_cast<short8*>(&Wb[(size_t)n * KP + c]) = v;
}

// ---------------- GEMM: xb = z @ W^T. BM=128, BN=320, BK=32, 8 waves (2Mw x 4Nw).
// Exact R13 structure (refchecked; 0 bank conflicts; 151 us measured floor).
__global__ __launch_bounds__(512) void gemm_x(const float* __restrict__ z,
                                              const unsigned short* __restrict__ Wb,
                                              const float* __restrict__ att_s,
                                              const float* __restrict__ att_d,
                                              unsigned short* __restrict__ xb,
                                              float* __restrict__ a_s,
                                              float* __restrict__ a_d) {
  __shared__ __align__(16) unsigned short As[2][BM * 32];     // 2 x 8 KB
  __shared__ __align__(16) unsigned short Bs[2][BNP * 32];    // 2 x 20 KB

  const int tid  = threadIdx.x;
  const int lane = tid & 63;
  const int wid  = tid >> 6;           // 0..7
  const int mw   = wid >> 2;           // 0..1: rows mw*64..
  const int nw   = wid & 3;            // 0..3: cols nw*80..
  const int lr   = lane & 15;
  const int lg   = lane >> 4;
  const int lrs  = (lr >> 1) & 3;      // read-side swizzle term
  const int m0   = blockIdx.x * BM;

  f32x4 zero4 = {0.f, 0.f, 0.f, 0.f};
  const float4 fz4 = make_float4(0.f, 0.f, 0.f, 0.f);
  f32x4 acc[4][5];
  #pragma unroll
  for (int mf = 0; mf < 4; ++mf)
    #pragma unroll
    for (int nj = 0; nj < 5; ++nj) acc[mf][nj] = zero4;

  const int ra  = tid >> 2;
  const int kaL = tid & 3;
  const int kaP = kaL ^ ((ra >> 1) & 3);
  const int am  = m0 + ra;
  float4 ga0, ga1;

  const int bgc = (lane & 3) ^ ((lane >> 3) & 3);

  #define LOADA(KT)                                                           \
    {                                                                         \
      int k = (KT) * 32 + kaL * 8;                                            \
      if (am < N_NODES && k + 8 <= IN_DIM) {                                  \
        const float4* p = reinterpret_cast<const float4*>(z + (size_t)am * IN_DIM + k); \
        ga0 = p[0]; ga1 = p[1];                                               \
      } else { ga0 = fz4; ga1 = fz4; }                                        \
    }

  #define WRITEA(BUF)                                                         \
    {                                                                         \
      short8 v;                                                               \
      v[0]=f2bf(ga0.x); v[1]=f2bf(ga0.y); v[2]=f2bf(ga0.z); v[3]=f2bf(ga0.w); \
      v[4]=f2bf(ga1.x); v[5]=f2bf(ga1.y); v[6]=f2bf(ga1.z); v[7]=f2bf(ga1.w); \
      *reinterpret_cast<short8*>(&As[BUF][ra * 32 + kaP * 8]) = v;            \
    }

  #define STAGEB(BUF, KT)                                                     \
    _Pragma("unroll")                                                         \
    for (int t5 = 0; t5 < 3; ++t5) {                                          \
      int j = wid + 8 * t5;                                                   \
      if (j < 20) {                                                           \
        const unsigned short* gsrc =                                          \
            Wb + (size_t)(j * 16 + (lane >> 2)) * KP + (KT) * 32 + bgc * 8;   \
        gl_lds16(gsrc, &Bs[BUF][j * 16 * 32]);                                \
      }                                                                       \
    }

  STAGEB(0, 0);
  LOADA(0);
  WRITEA(0);
  __syncthreads();

  #pragma unroll 1
  for (int kt = 0; kt < NKT; ++kt) {
    const int cur = kt & 1;
    if (kt < NKT - 1) {
      STAGEB(cur ^ 1, kt + 1);
      LOADA(kt + 1);
    }

    short8 a0 = *reinterpret_cast<const short8*>(&As[cur][(mw * 64 +      lr) * 32 + (lg ^ lrs) * 8]);
    short8 a1 = *reinterpret_cast<const short8*>(&As[cur][(mw * 64 + 16 + lr) * 32 + (lg ^ lrs) * 8]);
    short8 a2 = *reinterpret_cast<const short8*>(&As[cur][(mw * 64 + 32 + lr) * 32 + (lg ^ lrs) * 8]);
    short8 a3 = *reinterpret_cast<const short8*>(&As[cur][(mw * 64 + 48 + lr) * 32 + (lg ^ lrs) * 8]);
    #pragma unroll
    for (int nj = 0; nj < 5; ++nj) {
      short8 b = *reinterpret_cast<const short8*>(
          &Bs[cur][(nw * 80 + nj * 16 + lr) * 32 + (lg ^ lrs) * 8]);
      acc[0][nj] = __builtin_amdgcn_mfma_f32_16x16x32_bf16(a0, b, acc[0][nj], 0, 0, 0);
      acc[1][nj] = __builtin_amdgcn_mfma_f32_16x16x32_bf16(a1, b, acc[1][nj], 0, 0, 0);
      acc[2][nj] = __builtin_amdgcn_mfma_f32_16x16x32_bf16(a2, b, acc[2][nj], 0, 0, 0);
      acc[3][nj] = __builtin_amdgcn_mfma_f32_16x16x32_bf16(a3, b, acc[3][nj], 0, 0, 0);
    }

    if (kt < NKT - 1) { WRITEA(cur ^ 1); }
    __syncthreads();
  }
  #undef LOADA
  #undef WRITEA
  #undef STAGEB

  // ---- epilogue: bf16 x store + fused logits; reduce across 4 nw-waves via LDS
  float* red = reinterpret_cast<float*>(&As[0][0]);  // [2 sd][4 nw][128 rows] = 4 KB

  float ps[4][4], pd[4][4];
  #pragma unroll
  for (int mf = 0; mf < 4; ++mf)
    #pragma unroll
    for (int jj = 0; jj < 4; ++jj) { ps[mf][jj] = 0.f; pd[mf][jj] = 0.f; }

  #pragma unroll
  for (int nj = 0; nj < 5; ++nj) {
    int c = nw * 80 + nj * 16 + lr;
    bool cv = c < OUT_DIM;
    float vs = cv ? att_s[c] : 0.f;
    float vd = cv ? att_d[c] : 0.f;
    #pragma unroll
    for (int mf = 0; mf < 4; ++mf) {
      #pragma unroll
      for (int jj = 0; jj < 4; ++jj) {
        float val = acc[mf][nj][jj];
        int r = m0 + mw * 64 + mf * 16 + 4 * lg + jj;
        if (cv && r < N_NODES) xb[(size_t)r * XBS + c] = (unsigned short)f2bf(val);
        ps[mf][jj] += val * vs;
        pd[mf][jj] += val * vd;
      }
    }
  }
  #pragma unroll
  for (int mf = 0; mf < 4; ++mf)
    #pragma unroll
    for (int jj = 0; jj < 4; ++jj) {
      #pragma unroll
      for (int o = 8; o > 0; o >>= 1) {
        ps[mf][jj] += __shfl_xor(ps[mf][jj], o);
        pd[mf][jj] += __shfl_xor(pd[mf][jj], o);
      }
      if (lr == 0) {
        int rr = mw * 64 + mf * 16 + 4 * lg + jj;   // 0..127
        red[nw * 128 + rr]       = ps[mf][jj];
        red[512 + nw * 128 + rr] = pd[mf][jj];
      }
    }
  __syncthreads();
  if (tid < 128) {
    int r = m0 + tid;
    if (r < N_NODES)
      a_s[r] = red[tid] + red[128 + tid] + red[256 + tid] + red[384 + tid];
  } else if (tid < 256) {
    int t = tid - 128, r = m0 + t;
    if (r < N_NODES)
      a_d[r] = red[512 + t] + red[512 + 128 + t] + red[512 + 256 + t] + red[512 + 384 + t];
  }
}

// ---------------- CSR build: ei read as int4 (4 edges/thread, 16B coalesced)
__global__ void hist(const int* __restrict__ ei, int* __restrict__ deg) {
  int e4 = (blockIdx.x * blockDim.x + threadIdx.x) * 4;
  if (e4 < N_EDGES) {
    int4 d = *reinterpret_cast<const int4*>(ei + N_EDGES + e4);
    if ((unsigned)d.x < N_NODES) atomicAdd(&deg[d.x], 1);
    if ((unsigned)d.y < N_NODES) atomicAdd(&deg[d.y], 1);
    if ((unsigned)d.z < N_NODES) atomicAdd(&deg[d.z], 1);
    if ((unsigned)d.w < N_NODES) atomicAdd(&deg[d.w], 1);
  }
}

#define SCAN_B 1024
#define NBLK   49

__global__ __launch_bounds__(SCAN_B) void scan1(const int* __restrict__ deg,
                                                int* __restrict__ bsum) {
  int i = blockIdx.x * SCAN_B + threadIdx.x;
  int v = (i < N_NODES) ? deg[i] : 0;
  #pragma unroll
  for (int o = 32; o > 0; o >>= 1) v += __shfl_xor(v, o);
  __shared__ int wt[16];
  if ((threadIdx.x & 63) == 0) wt[threadIdx.x >> 6] = v;
  __syncthreads();
  if (threadIdx.x == 0) {
    int t = 0;
    #pragma unroll
    for (int w = 0; w < 16; ++w) t += wt[w];
    bsum[blockIdx.x] = t;
  }
}

__global__ void scan2(const int* __restrict__ bsum, int* __restrict__ bex,
                      int* __restrict__ offs) {
  int l = threadIdx.x;
  int v = (l < NBLK) ? bsum[l] : 0;
  int incl = v;
  #pragma unroll
  for (int off = 1; off < 64; off <<= 1) {
    int u = __shfl_up(incl, off);
    if (l >= off) incl += u;
  }
  if (l < NBLK) bex[l] = incl - v;
  if (l == NBLK - 1) offs[N_NODES] = incl;
}

__global__ __launch_bounds__(SCAN_B) void scan3(const int* __restrict__ deg,
                                                const int* __restrict__ bex,
                                                int* __restrict__ offs,
                                                int* __restrict__ cursor) {
  int tid = threadIdx.x;
  int i = blockIdx.x * SCAN_B + tid;
  int lane = tid & 63, wid = tid >> 6;
  int v = (i < N_NODES) ? deg[i] : 0;
  int incl = v;
  #pragma unroll
  for (int off = 1; off < 64; off <<= 1) {
    int u = __shfl_up(incl, off);
    if (lane >= off) incl += u;
  }
  __shared__ int wt[16];
  if (lane == 63) wt[wid] = incl;
  __syncthreads();
  if (tid < 16) {
    int t = wt[tid];
    int sc = t;
    #pragma unroll
    for (int off = 1; off < 16; off <<= 1) {
      int u = __shfl_up(sc, off);
      if (tid >= off) sc += u;
    }
    wt[tid] = sc - t;
  }
  __syncthreads();
  int excl = incl - v + wt[wid] + bex[blockIdx.x];
  if (i < N_NODES) { offs[i] = excl; cursor[i] = excl; }
}

__global__ void fill(const int* __restrict__ ei, int* __restrict__ cursor,
                     int* __restrict__ srcs) {
  int e4 = (blockIdx.x * blockDim.x + threadIdx.x) * 4;
  if (e4 < N_EDGES) {
    int4 s = *reinterpret_cast<const int4*>(ei + e4);
    int4 d = *reinterpret_cast<const int4*>(ei + N_EDGES + e4);
    if ((unsigned)d.x < N_NODES && (unsigned)s.x < N_NODES)
      srcs[atomicAdd(&cursor[d.x], 1)] = s.x;
    if ((unsigned)d.y < N_NODES && (unsigned)s.y < N_NODES)
      srcs[atomicAdd(&cursor[d.y], 1)] = s.y;
    if ((unsigned)d.z < N_NODES && (unsigned)s.z < N_NODES)
      srcs[atomicAdd(&cursor[d.z], 1)] = s.z;
    if ((unsigned)d.w < N_NODES && (unsigned)s.w < N_NODES)
      srcs[atomicAdd(&cursor[d.w], 1)] = s.w;
  }
}

// ---------------- per-node softmax stats (m, 1/s) — wave per node
__global__ __launch_bounds__(256) void minv_k(const float* __restrict__ a_s,
                                              const float* __restrict__ a_d,
                                              const int* __restrict__ offs,
                                              const int* __restrict__ srcs,
                                              float2* __restrict__ minv) {
  int node = blockIdx.x * 4 + (threadIdx.x >> 6);
  if (node >= N_NODES) return;
  int lane = threadIdx.x & 63;
  int beg = offs[node], end = offs[node + 1];
  float adi = a_d[node];
  float eself = lrelu(a_s[node] + adi);

  float m = eself;
  for (int k = beg + lane; k < end; k += 64)
    m = fmaxf(m, lrelu(a_s[srcs[k]] + adi));
  m = wredMaxF(m);

  float s = 0.f;
  for (int k = beg + lane; k < end; k += 64)
    s += expf(lrelu(a_s[srcs[k]] + adi) - m);
  s = wredSumF(s) + expf(eself - m);
  if (lane == 0) minv[node] = make_float2(m, 1.0f / s);
}

// ---------------- streaming weighted gather: thread = (node, 64-col chunk)
// CCH 15->5: metadata (srcs + a_s gather + exp) read 5x instead of 15x per
// edge; xb gather volume unchanged (row partitioned). 8 short8 loads/edge.
#define CCH 5
__global__ __launch_bounds__(256) void aggregate(const unsigned short* __restrict__ xb,
                                                 const float* __restrict__ a_s,
                                                 const float* __restrict__ a_d,
                                                 const float2* __restrict__ minv,
                                                 const int* __restrict__ offs,
                                                 const int* __restrict__ srcs,
                                                 const float* __restrict__ bias,
                                                 float* __restrict__ out) {
  unsigned wi = blockIdx.x * 256u + threadIdx.x;
  if (wi >= (unsigned)N_NODES * CCH) return;
  unsigned node = wi / CCH;
  unsigned cc = wi - node * CCH;           // chunk: cols [64cc, 64cc+64) clipped
  const int col0 = 64 * (int)cc;

  int beg = offs[node], end = offs[node + 1];
  float2 mi = minv[node];
  const float m = mi.x, inv = mi.y;
  const float adi = a_d[node];
  const float wself = expf(lrelu(a_s[node] + adi) - m) * inv;

  const unsigned short* xcol = xb + col0;

  // per-j validity: chunk j covers cols [col0+8j, col0+8j+8); xb row has XBS=304
  // cols (300 real + 4 pad, pad garbage but never stored).
  float acc[64];
  {
    const unsigned short* xr = xcol + (size_t)node * XBS;
    #pragma unroll
    for (int j = 0; j < 8; ++j) {
      short8 v = {0,0,0,0,0,0,0,0};
      if (col0 + 8 * j + 8 <= XBS) v = *reinterpret_cast<const short8*>(xr + 8 * j);
      #pragma unroll
      for (int q = 0; q < 8; ++q) acc[8*j+q] = wself * bf2f((unsigned short)v[q]);
    }
  }

  for (int k = beg; k < end; ++k) {
    int sj = srcs[k];
    float w = expf(lrelu(a_s[sj] + adi) - m) * inv;
    const unsigned short* xr = xcol + (size_t)sj * XBS;
    #pragma unroll
    for (int j = 0; j < 8; ++j) {
      if (col0 + 8 * j + 8 <= XBS) {
        short8 v = *reinterpret_cast<const short8*>(xr + 8 * j);
        #pragma unroll
        for (int q = 0; q < 8; ++q) acc[8*j+q] += w * bf2f((unsigned short)v[q]);
      }
    }
  }

  float* op = out + (size_t)node * OUT_DIM + col0;
  const float* bp = bias + col0;
  #pragma unroll
  for (int g = 0; g < 16; ++g) {
    int c = col0 + 4 * g;
    if (c + 4 <= OUT_DIM) {
      float4 b = *reinterpret_cast<const float4*>(bp + 4 * g);
      float4 o = {acc[4*g] + b.x, acc[4*g+1] + b.y, acc[4*g+2] + b.z, acc[4*g+3] + b.w};
      *reinterpret_cast<float4*>(op + 4 * g) = o;
    }
  }
}

extern "C" void kernel_launch(void* const* d_in, const int* in_sizes, int n_in,
                              void* d_out, int out_size, void* d_ws, size_t ws_size,
                              hipStream_t stream) {
  const float* z     = (const float*)d_in[0];
  const int*   ei    = (const int*)d_in[1];     // int64 in ref -> int32 on the wire
  const float* W     = (const float*)d_in[2];
  const float* att_s = (const float*)d_in[3];
  const float* att_d = (const float*)d_in[4];
  const float* bias  = (const float*)d_in[5];
  float* out = (float*)d_out;

  char* ws = (char*)d_ws;
  size_t off = 0;
  unsigned short* xb = (unsigned short*)(ws + off); off += (size_t)N_NODES * XBS * 2;  // 30.4 MB
  unsigned short* Wb = (unsigned short*)(ws + off); off += (size_t)BNP * KP * 2;
  float*  a_s  = (float*)(ws + off);  off += 50048 * 4;
  float*  a_d  = (float*)(ws + off);  off += 50048 * 4;
  int*    deg  = (int*)(ws + off);    off += 50048 * 4;
  int*    offs = (int*)(ws + off);    off += 50056 * 4;
  int*    cur  = (int*)(ws + off);    off += 50048 * 4;
  int*    bsum = (int*)(ws + off);    off += 64 * 4;
  int*    bex  = (int*)(ws + off);    off += 64 * 4;
  int*    srcs = (int*)(ws + off);    off += (size_t)N_EDGES * 4;
  float2* minv = (float2*)(ws + off); off += (size_t)50048 * 8;

  (void)hipMemsetAsync(deg, 0, N_NODES * 4, stream);

  wconv<<<(BNP * KP / 8 + 255) / 256, 256, 0, stream>>>(W, Wb);
  gemm_x<<<GRID_M, 512, 0, stream>>>(z, Wb, att_s, att_d, xb, a_s, a_d);
  hist<<<(N_EDGES / 4 + 255) / 256, 256, 0, stream>>>(ei, deg);
  scan1<<<NBLK, SCAN_B, 0, stream>>>(deg, bsum);
  scan2<<<1, 64, 0, stream>>>(bsum, bex, offs);
  scan3<<<NBLK, SCAN_B, 0, stream>>>(deg, bex, offs, cur);
  fill<<<(N_EDGES / 4 + 255) / 256, 256, 0, stream>>>(ei, cur, srcs);
  minv_k<<<(N_NODES + 3) / 4, 256, 0, stream>>>(a_s, a_d, offs, srcs, minv);
  aggregate<<<((unsigned)N_NODES * CCH + 255) / 256, 256, 0, stream>>>(
      xb, a_s, a_d, minv, offs, srcs, bias, out);
}

// Round 18
// 333.042 us; speedup vs baseline: 1.3636x; 1.3287x over previous
//
#include <hip/hip_runtime.h>

#define N_NODES 50000
#define N_EDGES 800000
#define IN_DIM  1200
#define KP      1216               // Wb padded K
#define OUT_DIM 300
#define BNP     320                // Wb padded rows
#define XBS     304                // xb row stride (bf16)
#define BM      128
#define NKT     38                 // K-steps of 32
#define GRID_M  ((N_NODES + BM - 1) / BM)   // 391

typedef __attribute__((ext_vector_type(8))) short short8;
typedef __attribute__((ext_vector_type(4))) float f32x4;

__device__ __forceinline__ short f2bf(float f) {
  unsigned u = __builtin_bit_cast(unsigned, f);
  u += 0x7fffu + ((u >> 16) & 1u);            // RNE
  return (short)(u >> 16);
}
__device__ __forceinline__ float bf2f(unsigned short h) {
  return __builtin_bit_cast(float, (unsigned)h << 16);
}
__device__ __forceinline__ float lrelu(float v) { return v > 0.f ? v : 0.2f * v; }

__device__ __forceinline__ float wredMaxF(float v) {
  #pragma unroll
  for (int o = 32; o > 0; o >>= 1) v = fmaxf(v, __shfl_xor(v, o));
  return v;
}
__device__ __forceinline__ float wredSumF(float v) {
  #pragma unroll
  for (int o = 32; o > 0; o >>= 1) v += __shfl_xor(v, o);
  return v;
}

// async 16B/lane global->LDS DMA; lds dest wave-uniform (HW adds lane*16)
__device__ __forceinline__ void gl_lds16(const unsigned short* g, unsigned short* l) {
  __builtin_amdgcn_global_load_lds(
      (const __attribute__((address_space(1))) unsigned int*)g,
      (__attribute__((address_space(3))) unsigned int*)l, 16, 0, 0);
}

// ---------------- W -> bf16, padded [320][1216]
__global__ __launch_bounds__(256) void wconv(const float* __restrict__ W,
                                             unsigned short* __restrict__ Wb) {
  int f = blockIdx.x * 256 + threadIdx.x;
  if (f >= BNP * KP / 8) return;
  int n = (f * 8) / KP, c = (f * 8) % KP;
  short8 v = {0,0,0,0,0,0,0,0};
  if (n < OUT_DIM && c < IN_DIM) {
    const float4* p = reinterpret_cast<const float4*>(W + (size_t)n * IN_DIM + c);
    float4 f0 = p[0], f1 = p[1];
    v[0]=f2bf(f0.x); v[1]=f2bf(f0.y); v[2]=f2bf(f0.z); v[3]=f2bf(f0.w);
    v[4]=f2bf(f1.x); v[5]=f2bf(f1.y); v[6]=f2bf(f1.z); v[7]=f2bf(f1.w);
  }
  *reinterpret_cast<short8*>(&Wb[(size_t)n * KP + c]) = v;
}

// ---------------- GEMM: xb = z @ W^T. BM=128, BN=320, BK=32, 8 waves (2Mw x 4Nw).
// Exact R13 structure (refchecked; 0 bank conflicts; 151 us measured floor).
__global__ __launch_bounds__(512) void gemm_x(const float* __restrict__ z,
                                              const unsigned short* __restrict__ Wb,
                                              const float* __restrict__ att_s,
                                              const float* __restrict__ att_d,
                                              unsigned short* __restrict__ xb,
                                              float* __restrict__ a_s,
                                              float* __restrict__ a_d) {
  __shared__ __align__(16) unsigned short As[2][BM * 32];     // 2 x 8 KB
  __shared__ __align__(16) unsigned short Bs[2][BNP * 32];    // 2 x 20 KB

  const int tid  = threadIdx.x;
  const int lane = tid & 63;
  const int wid  = tid >> 6;           // 0..7
  const int mw   = wid >> 2;           // 0..1: rows mw*64..
  const int nw   = wid & 3;            // 0..3: cols nw*80..
  const int lr   = lane & 15;
  const int lg   = lane >> 4;
  const int lrs  = (lr >> 1) & 3;      // read-side swizzle term
  const int m0   = blockIdx.x * BM;

  f32x4 zero4 = {0.f, 0.f, 0.f, 0.f};
  const float4 fz4 = make_float4(0.f, 0.f, 0.f, 0.f);
  f32x4 acc[4][5];
  #pragma unroll
  for (int mf = 0; mf < 4; ++mf)
    #pragma unroll
    for (int nj = 0; nj < 5; ++nj) acc[mf][nj] = zero4;

  const int ra  = tid >> 2;
  const int kaL = tid & 3;
  const int kaP = kaL ^ ((ra >> 1) & 3);
  const int am  = m0 + ra;
  float4 ga0, ga1;

  const int bgc = (lane & 3) ^ ((lane >> 3) & 3);

  #define LOADA(KT)                                                           \
    {                                                                         \
      int k = (KT) * 32 + kaL * 8;                                            \
      if (am < N_NODES && k + 8 <= IN_DIM) {                                  \
        const float4* p = reinterpret_cast<const float4*>(z + (size_t)am * IN_DIM + k); \
        ga0 = p[0]; ga1 = p[1];                                               \
      } else { ga0 = fz4; ga1 = fz4; }                                        \
    }

  #define WRITEA(BUF)                                                         \
    {                                                                         \
      short8 v;                                                               \
      v[0]=f2bf(ga0.x); v[1]=f2bf(ga0.y); v[2]=f2bf(ga0.z); v[3]=f2bf(ga0.w); \
      v[4]=f2bf(ga1.x); v[5]=f2bf(ga1.y); v[6]=f2bf(ga1.z); v[7]=f2bf(ga1.w); \
      *reinterpret_cast<short8*>(&As[BUF][ra * 32 + kaP * 8]) = v;            \
    }

  #define STAGEB(BUF, KT)                                                     \
    _Pragma("unroll")                                                         \
    for (int t5 = 0; t5 < 3; ++t5) {                                          \
      int j = wid + 8 * t5;                                                   \
      if (j < 20) {                                                           \
        const unsigned short* gsrc =                                          \
            Wb + (size_t)(j * 16 + (lane >> 2)) * KP + (KT) * 32 + bgc * 8;   \
        gl_lds16(gsrc, &Bs[BUF][j * 16 * 32]);                                \
      }                                                                       \
    }

  STAGEB(0, 0);
  LOADA(0);
  WRITEA(0);
  __syncthreads();

  #pragma unroll 1
  for (int kt = 0; kt < NKT; ++kt) {
    const int cur = kt & 1;
    if (kt < NKT - 1) {
      STAGEB(cur ^ 1, kt + 1);
      LOADA(kt + 1);
    }

    short8 a0 = *reinterpret_cast<const short8*>(&As[cur][(mw * 64 +      lr) * 32 + (lg ^ lrs) * 8]);
    short8 a1 = *reinterpret_cast<const short8*>(&As[cur][(mw * 64 + 16 + lr) * 32 + (lg ^ lrs) * 8]);
    short8 a2 = *reinterpret_cast<const short8*>(&As[cur][(mw * 64 + 32 + lr) * 32 + (lg ^ lrs) * 8]);
    short8 a3 = *reinterpret_cast<const short8*>(&As[cur][(mw * 64 + 48 + lr) * 32 + (lg ^ lrs) * 8]);
    #pragma unroll
    for (int nj = 0; nj < 5; ++nj) {
      short8 b = *reinterpret_cast<const short8*>(
          &Bs[cur][(nw * 80 + nj * 16 + lr) * 32 + (lg ^ lrs) * 8]);
      acc[0][nj] = __builtin_amdgcn_mfma_f32_16x16x32_bf16(a0, b, acc[0][nj], 0, 0, 0);
      acc[1][nj] = __builtin_amdgcn_mfma_f32_16x16x32_bf16(a1, b, acc[1][nj], 0, 0, 0);
      acc[2][nj] = __builtin_amdgcn_mfma_f32_16x16x32_bf16(a2, b, acc[2][nj], 0, 0, 0);
      acc[3][nj] = __builtin_amdgcn_mfma_f32_16x16x32_bf16(a3, b, acc[3][nj], 0, 0, 0);
    }

    if (kt < NKT - 1) { WRITEA(cur ^ 1); }
    __syncthreads();
  }
  #undef LOADA
  #undef WRITEA
  #undef STAGEB

  // ---- epilogue: bf16 x store + fused logits; reduce across 4 nw-waves via LDS
  float* red = reinterpret_cast<float*>(&As[0][0]);  // [2 sd][4 nw][128 rows] = 4 KB

  float ps[4][4], pd[4][4];
  #pragma unroll
  for (int mf = 0; mf < 4; ++mf)
    #pragma unroll
    for (int jj = 0; jj < 4; ++jj) { ps[mf][jj] = 0.f; pd[mf][jj] = 0.f; }

  #pragma unroll
  for (int nj = 0; nj < 5; ++nj) {
    int c = nw * 80 + nj * 16 + lr;
    bool cv = c < OUT_DIM;
    float vs = cv ? att_s[c] : 0.f;
    float vd = cv ? att_d[c] : 0.f;
    #pragma unroll
    for (int mf = 0; mf < 4; ++mf) {
      #pragma unroll
      for (int jj = 0; jj < 4; ++jj) {
        float val = acc[mf][nj][jj];
        int r = m0 + mw * 64 + mf * 16 + 4 * lg + jj;
        if (cv && r < N_NODES) xb[(size_t)r * XBS + c] = (unsigned short)f2bf(val);
        ps[mf][jj] += val * vs;
        pd[mf][jj] += val * vd;
      }
    }
  }
  #pragma unroll
  for (int mf = 0; mf < 4; ++mf)
    #pragma unroll
    for (int jj = 0; jj < 4; ++jj) {
      #pragma unroll
      for (int o = 8; o > 0; o >>= 1) {
        ps[mf][jj] += __shfl_xor(ps[mf][jj], o);
        pd[mf][jj] += __shfl_xor(pd[mf][jj], o);
      }
      if (lr == 0) {
        int rr = mw * 64 + mf * 16 + 4 * lg + jj;   // 0..127
        red[nw * 128 + rr]       = ps[mf][jj];
        red[512 + nw * 128 + rr] = pd[mf][jj];
      }
    }
  __syncthreads();
  if (tid < 128) {
    int r = m0 + tid;
    if (r < N_NODES)
      a_s[r] = red[tid] + red[128 + tid] + red[256 + tid] + red[384 + tid];
  } else if (tid < 256) {
    int t = tid - 128, r = m0 + t;
    if (r < N_NODES)
      a_d[r] = red[512 + t] + red[512 + 128 + t] + red[512 + 256 + t] + red[512 + 384 + t];
  }
}

// ---------------- CSR build: ei read as int4 (4 edges/thread, 16B coalesced)
__global__ void hist(const int* __restrict__ ei, int* __restrict__ deg) {
  int e4 = (blockIdx.x * blockDim.x + threadIdx.x) * 4;
  if (e4 < N_EDGES) {
    int4 d = *reinterpret_cast<const int4*>(ei + N_EDGES + e4);
    if ((unsigned)d.x < N_NODES) atomicAdd(&deg[d.x], 1);
    if ((unsigned)d.y < N_NODES) atomicAdd(&deg[d.y], 1);
    if ((unsigned)d.z < N_NODES) atomicAdd(&deg[d.z], 1);
    if ((unsigned)d.w < N_NODES) atomicAdd(&deg[d.w], 1);
  }
}

#define SCAN_B 1024
#define NBLK   49

__global__ __launch_bounds__(SCAN_B) void scan1(const int* __restrict__ deg,
                                                int* __restrict__ bsum) {
  int i = blockIdx.x * SCAN_B + threadIdx.x;
  int v = (i < N_NODES) ? deg[i] : 0;
  #pragma unroll
  for (int o = 32; o > 0; o >>= 1) v += __shfl_xor(v, o);
  __shared__ int wt[16];
  if ((threadIdx.x & 63) == 0) wt[threadIdx.x >> 6] = v;
  __syncthreads();
  if (threadIdx.x == 0) {
    int t = 0;
    #pragma unroll
    for (int w = 0; w < 16; ++w) t += wt[w];
    bsum[blockIdx.x] = t;
  }
}

__global__ void scan2(const int* __restrict__ bsum, int* __restrict__ bex,
                      int* __restrict__ offs) {
  int l = threadIdx.x;
  int v = (l < NBLK) ? bsum[l] : 0;
  int incl = v;
  #pragma unroll
  for (int off = 1; off < 64; off <<= 1) {
    int u = __shfl_up(incl, off);
    if (l >= off) incl += u;
  }
  if (l < NBLK) bex[l] = incl - v;
  if (l == NBLK - 1) offs[N_NODES] = incl;
}

__global__ __launch_bounds__(SCAN_B) void scan3(const int* __restrict__ deg,
                                                const int* __restrict__ bex,
                                                int* __restrict__ offs,
                                                int* __restrict__ cursor) {
  int tid = threadIdx.x;
  int i = blockIdx.x * SCAN_B + tid;
  int lane = tid & 63, wid = tid >> 6;
  int v = (i < N_NODES) ? deg[i] : 0;
  int incl = v;
  #pragma unroll
  for (int off = 1; off < 64; off <<= 1) {
    int u = __shfl_up(incl, off);
    if (lane >= off) incl += u;
  }
  __shared__ int wt[16];
  if (lane == 63) wt[wid] = incl;
  __syncthreads();
  if (tid < 16) {
    int t = wt[tid];
    int sc = t;
    #pragma unroll
    for (int off = 1; off < 16; off <<= 1) {
      int u = __shfl_up(sc, off);
      if (tid >= off) sc += u;
    }
    wt[tid] = sc - t;
  }
  __syncthreads();
  int excl = incl - v + wt[wid] + bex[blockIdx.x];
  if (i < N_NODES) { offs[i] = excl; cursor[i] = excl; }
}

__global__ void fill(const int* __restrict__ ei, int* __restrict__ cursor,
                     int* __restrict__ srcs) {
  int e4 = (blockIdx.x * blockDim.x + threadIdx.x) * 4;
  if (e4 < N_EDGES) {
    int4 s = *reinterpret_cast<const int4*>(ei + e4);
    int4 d = *reinterpret_cast<const int4*>(ei + N_EDGES + e4);
    if ((unsigned)d.x < N_NODES && (unsigned)s.x < N_NODES)
      srcs[atomicAdd(&cursor[d.x], 1)] = s.x;
    if ((unsigned)d.y < N_NODES && (unsigned)s.y < N_NODES)
      srcs[atomicAdd(&cursor[d.y], 1)] = s.y;
    if ((unsigned)d.z < N_NODES && (unsigned)s.z < N_NODES)
      srcs[atomicAdd(&cursor[d.z], 1)] = s.z;
    if ((unsigned)d.w < N_NODES && (unsigned)s.w < N_NODES)
      srcs[atomicAdd(&cursor[d.w], 1)] = s.w;
  }
}

// ---------------- per-node softmax stats (m, 1/s) — wave per node
__global__ __launch_bounds__(256) void minv_k(const float* __restrict__ a_s,
                                              const float* __restrict__ a_d,
                                              const int* __restrict__ offs,
                                              const int* __restrict__ srcs,
                                              float2* __restrict__ minv) {
  int node = blockIdx.x * 4 + (threadIdx.x >> 6);
  if (node >= N_NODES) return;
  int lane = threadIdx.x & 63;
  int beg = offs[node], end = offs[node + 1];
  float adi = a_d[node];
  float eself = lrelu(a_s[node] + adi);

  float m = eself;
  for (int k = beg + lane; k < end; k += 64)
    m = fmaxf(m, lrelu(a_s[srcs[k]] + adi));
  m = wredMaxF(m);

  float s = 0.f;
  for (int k = beg + lane; k < end; k += 64)
    s += expf(lrelu(a_s[srcs[k]] + adi) - m);
  s = wredSumF(s) + expf(eself - m);
  if (lane == 0) minv[node] = make_float2(m, 1.0f / s);
}

// ---------------- streaming weighted gather: thread = (node, 20-col chunk)
// CCH=15 is the measured TLP optimum (R15: 1 wave/node worse; R17: CCH=5 worse).
#define CCH 15
__global__ __launch_bounds__(256) void aggregate(const unsigned short* __restrict__ xb,
                                                 const float* __restrict__ a_s,
                                                 const float* __restrict__ a_d,
                                                 const float2* __restrict__ minv,
                                                 const int* __restrict__ offs,
                                                 const int* __restrict__ srcs,
                                                 const float* __restrict__ bias,
                                                 float* __restrict__ out) {
  unsigned wi = blockIdx.x * 256u + threadIdx.x;
  if (wi >= (unsigned)N_NODES * CCH) return;
  unsigned node = wi / CCH;
  unsigned cc = wi - node * CCH;           // cols 20cc..20cc+19

  int beg = offs[node], end = offs[node + 1];
  float2 mi = minv[node];
  const float m = mi.x, inv = mi.y;
  const float adi = a_d[node];
  const float wself = expf(lrelu(a_s[node] + adi) - m) * inv;

  const unsigned short* xcol = xb + 20u * cc;

  float acc[20];
  {
    const unsigned short* xr = xcol + (size_t)node * XBS;
    #pragma unroll
    for (int q = 0; q < 5; ++q) {
      ushort4 xv = *reinterpret_cast<const ushort4*>(xr + 4 * q);
      acc[4*q+0] = wself * bf2f(xv.x);
      acc[4*q+1] = wself * bf2f(xv.y);
      acc[4*q+2] = wself * bf2f(xv.z);
      acc[4*q+3] = wself * bf2f(xv.w);
    }
  }

  for (int k = beg; k < end; ++k) {
    int sj = srcs[k];
    float w = expf(lrelu(a_s[sj] + adi) - m) * inv;
    const unsigned short* xr = xcol + (size_t)sj * XBS;
    #pragma unroll
    for (int q = 0; q < 5; ++q) {
      ushort4 xv = *reinterpret_cast<const ushort4*>(xr + 4 * q);
      acc[4*q+0] += w * bf2f(xv.x);
      acc[4*q+1] += w * bf2f(xv.y);
      acc[4*q+2] += w * bf2f(xv.z);
      acc[4*q+3] += w * bf2f(xv.w);
    }
  }
  float* op = out + (size_t)node * OUT_DIM + 20u * cc;
  const float* bp = bias + 20u * cc;
  #pragma unroll
  for (int q = 0; q < 5; ++q) {
    float4 b = *reinterpret_cast<const float4*>(bp + 4 * q);
    float4 o = {acc[4*q] + b.x, acc[4*q+1] + b.y, acc[4*q+2] + b.z, acc[4*q+3] + b.w};
    *reinterpret_cast<float4*>(op + 4 * q) = o;
  }
}

extern "C" void kernel_launch(void* const* d_in, const int* in_sizes, int n_in,
                              void* d_out, int out_size, void* d_ws, size_t ws_size,
                              hipStream_t stream) {
  const float* z     = (const float*)d_in[0];
  const int*   ei    = (const int*)d_in[1];     // int64 in ref -> int32 on the wire
  const float* W     = (const float*)d_in[2];
  const float* att_s = (const float*)d_in[3];
  const float* att_d = (const float*)d_in[4];
  const float* bias  = (const float*)d_in[5];
  float* out = (float*)d_out;

  char* ws = (char*)d_ws;
  size_t off = 0;
  unsigned short* xb = (unsigned short*)(ws + off); off += (size_t)N_NODES * XBS * 2;  // 30.4 MB
  unsigned short* Wb = (unsigned short*)(ws + off); off += (size_t)BNP * KP * 2;
  float*  a_s  = (float*)(ws + off);  off += 50048 * 4;
  float*  a_d  = (float*)(ws + off);  off += 50048 * 4;
  int*    deg  = (int*)(ws + off);    off += 50048 * 4;
  int*    offs = (int*)(ws + off);    off += 50056 * 4;
  int*    cur  = (int*)(ws + off);    off += 50048 * 4;
  int*    bsum = (int*)(ws + off);    off += 64 * 4;
  int*    bex  = (int*)(ws + off);    off += 64 * 4;
  int*    srcs = (int*)(ws + off);    off += (size_t)N_EDGES * 4;
  float2* minv = (float2*)(ws + off); off += (size_t)50048 * 8;

  (void)hipMemsetAsync(deg, 0, N_NODES * 4, stream);

  wconv<<<(BNP * KP / 8 + 255) / 256, 256, 0, stream>>>(W, Wb);
  gemm_x<<<GRID_M, 512, 0, stream>>>(z, Wb, att_s, att_d, xb, a_s, a_d);
  hist<<<(N_EDGES / 4 + 255) / 256, 256, 0, stream>>>(ei, deg);
  scan1<<<NBLK, SCAN_B, 0, stream>>>(deg, bsum);
  scan2<<<1, 64, 0, stream>>>(bsum, bex, offs);
  scan3<<<NBLK, SCAN_B, 0, stream>>>(deg, bex, offs, cur);
  fill<<<(N_EDGES / 4 + 255) / 256, 256, 0, stream>>>(ei, cur, srcs);
  minv_k<<<(N_NODES + 3) / 4, 256, 0, stream>>>(a_s, a_d, offs, srcs, minv);
  aggregate<<<((unsigned)N_NODES * CCH + 255) / 256, 256, 0, stream>>>(
      xb, a_s, a_d, minv, offs, srcs, bias, out);
}